// Round 5
// baseline (49426.590 us; speedup 1.0000x reference)
//
#include <hip/hip_runtime.h>
#include <math.h>

// Trajectory2seq — correctness round: fp64 scalar internals, FP32 OUTPUT.
// Root cause of rounds 2-4 (bit-identical absmax 0.51953125): output buffer
// is FLOAT32 (reference returns fp32; harness rule "bf16->bf16*, else float*"),
// but we stored packed bf16 uint16s -> read back as fp32 garbage in ±0.5.
// This round: identical structure to round 4, storing fp32.

#define Bb   256
#define Tt   128
#define Hh   1024
#define Vv   64
#define LIN  457
#define ML   64

// ---------------- fp64 dot helpers: 4 batch rows x 1 weight row ------------
static __device__ __forceinline__ void dot4d(const double* __restrict__ x0,
                                             const double* __restrict__ x1,
                                             const double* __restrict__ x2,
                                             const double* __restrict__ x3,
                                             const float* __restrict__ wr,
                                             int K, double acc[4]) {
#pragma unroll 4
    for (int k = 0; k < K; k++) {
        double wv = (double)wr[k];
        acc[0] = fma(x0[k], wv, acc[0]);
        acc[1] = fma(x1[k], wv, acc[1]);
        acc[2] = fma(x2[k], wv, acc[2]);
        acc[3] = fma(x3[k], wv, acc[3]);
    }
}
static __device__ __forceinline__ void dot4f(const float* __restrict__ x0,
                                             const float* __restrict__ x1,
                                             const float* __restrict__ x2,
                                             const float* __restrict__ x3,
                                             const float* __restrict__ wr,
                                             int K, double acc[4]) {
#pragma unroll 4
    for (int k = 0; k < K; k++) {
        double wv = (double)wr[k];
        acc[0] = fma((double)x0[k], wv, acc[0]);
        acc[1] = fma((double)x1[k], wv, acc[1]);
        acc[2] = fma((double)x2[k], wv, acc[2]);
        acc[3] = fma((double)x3[k], wv, acc[3]);
    }
}

// ------ encoder layer 0: o = tanh(x_t @ W0^T + h @ U0^T + b0), fp64 --------
__global__ __launch_bounds__(256) void enc0_k(
    const float* __restrict__ x, int t,
    const float* __restrict__ W0, const double* __restrict__ h,
    const float* __restrict__ U0, const float* __restrict__ b0,
    double* __restrict__ o) {
    const int n = blockIdx.x * 256 + threadIdx.x;
    const int b = blockIdx.y * 4;
    double acc[4];
    const double bv = (double)b0[n];
    acc[0] = acc[1] = acc[2] = acc[3] = bv;
    dot4f(x + ((size_t)(b + 0) * Tt + t) * LIN,
          x + ((size_t)(b + 1) * Tt + t) * LIN,
          x + ((size_t)(b + 2) * Tt + t) * LIN,
          x + ((size_t)(b + 3) * Tt + t) * LIN,
          W0 + (size_t)n * LIN, LIN, acc);
    dot4d(h + (size_t)(b + 0) * Hh, h + (size_t)(b + 1) * Hh,
          h + (size_t)(b + 2) * Hh, h + (size_t)(b + 3) * Hh,
          U0 + (size_t)n * Hh, Hh, acc);
#pragma unroll
    for (int r = 0; r < 4; r++) o[(size_t)(b + r) * Hh + n] = tanh(acc[r]);
}

// ---- layer-1 step (enc L1 / dec L1): o = tanh(xs@Wi^T + h@Wh^T + b) -------
__global__ __launch_bounds__(256) void rnn2_k(
    const double* __restrict__ xs, const float* __restrict__ Wi,
    const double* __restrict__ h,  const float* __restrict__ Wh,
    const float* __restrict__ bias, double* __restrict__ o) {
    const int n = blockIdx.x * 256 + threadIdx.x;
    const int b = blockIdx.y * 4;
    double acc[4];
    const double bv = (double)bias[n];
    acc[0] = acc[1] = acc[2] = acc[3] = bv;
    dot4d(xs + (size_t)(b + 0) * Hh, xs + (size_t)(b + 1) * Hh,
          xs + (size_t)(b + 2) * Hh, xs + (size_t)(b + 3) * Hh,
          Wi + (size_t)n * Hh, Hh, acc);
    dot4d(h + (size_t)(b + 0) * Hh, h + (size_t)(b + 1) * Hh,
          h + (size_t)(b + 2) * Hh, h + (size_t)(b + 3) * Hh,
          Wh + (size_t)n * Hh, Hh, acc);
#pragma unroll
    for (int r = 0; r < 4; r++) o[(size_t)(b + r) * Hh + n] = tanh(acc[r]);
}

// ---- decoder layer 0: o = tanh(EP[tok] + h @ U^T), EP holds e@W^T+b -------
__global__ __launch_bounds__(256) void dec0_k(
    const double* __restrict__ EP, const int* __restrict__ tok,
    const double* __restrict__ h, const float* __restrict__ U,
    double* __restrict__ o) {
    const int n = blockIdx.x * 256 + threadIdx.x;
    const int b = blockIdx.y * 4;
    double acc[4];
#pragma unroll
    for (int r = 0; r < 4; r++) acc[r] = EP[(size_t)tok[b + r] * Hh + n];
    dot4d(h + (size_t)(b + 0) * Hh, h + (size_t)(b + 1) * Hh,
          h + (size_t)(b + 2) * Hh, h + (size_t)(b + 3) * Hh,
          U + (size_t)n * Hh, Hh, acc);
#pragma unroll
    for (int r = 0; r < 4; r++) o[(size_t)(b + r) * Hh + n] = tanh(acc[r]);
}

// ------- one-time: EP[v][n] = emb[v] @ dec_Wih0^T + dec_b0 (fp64) ----------
__global__ __launch_bounds__(256) void dpre_k(const float* __restrict__ emb,
                                              const float* __restrict__ W,
                                              const float* __restrict__ b,
                                              double* __restrict__ EP) {
    const int n = blockIdx.x * 256 + threadIdx.x;
    const int v = blockIdx.y * 4;
    double acc[4];
    const double bv = (double)b[n];
    acc[0] = acc[1] = acc[2] = acc[3] = bv;
    dot4f(emb + (size_t)(v + 0) * Hh, emb + (size_t)(v + 1) * Hh,
          emb + (size_t)(v + 2) * Hh, emb + (size_t)(v + 3) * Hh,
          W + (size_t)n * Hh, Hh, acc);
#pragma unroll
    for (int r = 0; r < 4; r++) EP[(size_t)(v + r) * Hh + n] = acc[r];
}

// ------ fc + argmax + FP32 logit store; wave per batch row, fp64 -----------
__global__ __launch_bounds__(256) void fc_k(const double* __restrict__ h1,
                                            const float* __restrict__ fcw,
                                            const float* __restrict__ fcb,
                                            float* __restrict__ out,
                                            int* __restrict__ tok, int t) {
    const int w = threadIdx.x >> 6, v = threadIdx.x & 63;
    const int b = blockIdx.x * 4 + w;
    const double* hr = h1 + (size_t)b * Hh;   // wave-uniform row
    const float* wr = fcw + (size_t)v * Hh;   // per-lane row
    double acc = (double)fcb[v];
#pragma unroll 4
    for (int k = 0; k < Hh; k++) acc = fma(hr[k], (double)wr[k], acc);
    out[(size_t)b * (Vv * ML) + (size_t)v * ML + t] = (float)acc;
    // wave argmax over V=64 lanes, first-index tiebreak (np.argmax)
    double bvv = acc;
    int bi = v;
#pragma unroll
    for (int s = 1; s < 64; s <<= 1) {
        double ov = __shfl_xor(bvv, s, 64);
        int oi = __shfl_xor(bi, s, 64);
        if (ov > bvv || (ov == bvv && oi < bi)) { bvv = ov; bi = oi; }
    }
    if (v == 0) tok[b] = bi;
}

// ------------------------- final hidden output (fp32) ----------------------
__global__ __launch_bounds__(256) void wh_k(const double* __restrict__ h0,
                                            const double* __restrict__ h1,
                                            float* __restrict__ out) {
    int i = blockIdx.x * 256 + threadIdx.x;   // B*H = 262144 per layer
    const size_t base = (size_t)Bb * Vv * ML;
    out[base + i] = (float)h0[i];
    out[base + (size_t)Bb * Hh + i] = (float)h1[i];
}

// ---------------------------------------------------------------------------
extern "C" void kernel_launch(void* const* d_in, const int* in_sizes, int n_in,
                              void* d_out, int out_size, void* d_ws, size_t ws_size,
                              hipStream_t stream) {
    const float* x   = (const float*)d_in[0];
    const float* emb = (const float*)d_in[1];
    const float* eW0 = (const float*)d_in[2];   // [1024,457]
    const float* eU0 = (const float*)d_in[3];   // [1024,1024]
    const float* eb0 = (const float*)d_in[4];
    const float* eW1 = (const float*)d_in[5];
    const float* eU1 = (const float*)d_in[6];
    const float* eb1 = (const float*)d_in[7];
    const float* dW0 = (const float*)d_in[8];
    const float* dU0 = (const float*)d_in[9];
    const float* db0 = (const float*)d_in[10];
    const float* dW1 = (const float*)d_in[11];
    const float* dU1 = (const float*)d_in[12];
    const float* db1 = (const float*)d_in[13];
    const float* fcw = (const float*)d_in[14];
    const float* fcb = (const float*)d_in[15];
    (void)in_sizes; (void)n_in; (void)out_size; (void)ws_size;

    char* ws = (char*)d_ws;
    const size_t SB = (size_t)Bb * Hh * 8;      // 2 MB fp64 state
    size_t o = 0;
    double* h0[2]; double* h1[2];
    h0[0] = (double*)(ws + o); o += SB;
    h1[0] = (double*)(ws + o); o += SB;
    int* tok = (int*)(ws + o); o += 4096;
    const size_t zero_bytes = o;                // initial state + start tokens
    h0[1] = (double*)(ws + o); o += SB;
    h1[1] = (double*)(ws + o); o += SB;
    double* EP = (double*)(ws + o); o += (size_t)Vv * Hh * 8;
    // total ~8.6 MB

    hipMemsetAsync(ws, 0, zero_bytes, stream);
    dim3 blk(256);
    dim3 g(Hh / 256, Bb / 4);                   // (4, 64) = 256 blocks
    dim3 gp(Hh / 256, Vv / 4);                  // (4, 16)
    float* out = (float*)d_out;

    for (int t = 0; t < Tt; t++) {
        int in = t & 1, op = in ^ 1;
        enc0_k<<<g, blk, 0, stream>>>(x, t, eW0, h0[in], eU0, eb0, h0[op]);
        rnn2_k<<<g, blk, 0, stream>>>(h0[op], eW1, h1[in], eU1, eb1, h1[op]);
    }
    dpre_k<<<gp, blk, 0, stream>>>(emb, dW0, db0, EP);
    for (int s = 0; s < ML; s++) {
        int in = s & 1, op = in ^ 1;
        dec0_k<<<g, blk, 0, stream>>>(EP, tok, h0[in], dU0, h0[op]);
        rnn2_k<<<g, blk, 0, stream>>>(h0[op], dW1, h1[in], dU1, db1, h1[op]);
        fc_k<<<dim3(Bb / 4), blk, 0, stream>>>(h1[op], fcw, fcb, out, tok, s);
    }
    wh_k<<<dim3(Bb * Hh / 256), blk, 0, stream>>>(h0[0], h1[0], out);
}

// Round 6
// 30970.941 us; speedup vs baseline: 1.5959x; 1.5959x over previous
//
#include <hip/hip_runtime.h>
#include <math.h>

// Trajectory2seq: 2-layer tanh RNN encoder (T=128, B=256, H=1024) + greedy
// autoregressive decoder (64 steps). Inputs fp32, OUTPUT FP32 (round-5 fix).
// Recurrent GEMMs: bf16 MFMA, 2-way hi/lo split of state and weights,
// 3 passes -> ~1e-5 logit error vs fp32 ref; measured argmax gap margin
// ~1e-3 (round 5: fp64 impl deviated 4.9e-4 from np-fp32 ref, zero flips).
// Token-deciding fc + argmax kept in fp64 VALU.

#define Bb   256
#define Tt   128
#define Hh   1024
#define Vv   64
#define LIN  457
#define LPAD 480   // 457 padded to 15*32; bf16 rows 960B = 16B-aligned
#define ML   64

typedef __bf16 bf16;
typedef __bf16 bf16x8 __attribute__((ext_vector_type(8)));
typedef float  f32x4  __attribute__((ext_vector_type(4)));

static __device__ __forceinline__ float bf2f(bf16 x) {
    unsigned short u = __builtin_bit_cast(unsigned short, x);
    unsigned int w = ((unsigned int)u) << 16;
    return __builtin_bit_cast(float, w);
}
static __device__ __forceinline__ unsigned short f2bfbits(float f) {
    unsigned int u = __builtin_bit_cast(unsigned int, f);
    u = u + 0x7FFFu + ((u >> 16) & 1u);   // RNE (finite only)
    return (unsigned short)(u >> 16);
}
static __device__ __forceinline__ bf16 f2bf(float f) {
    return __builtin_bit_cast(bf16, f2bfbits(f));
}

#define MFMA(a, b, c) __builtin_amdgcn_mfma_f32_16x16x32_bf16((a), (b), (c), 0, 0, 0)

// ------------------- one-time fp32 -> bf16 hi/lo splits --------------------
__global__ __launch_bounds__(256) void split_k(const float* __restrict__ src,
                                               bf16* __restrict__ hi,
                                               bf16* __restrict__ lo, int n) {
    int i = blockIdx.x * 256 + threadIdx.x;
    if (i < n) {
        float v = src[i];
        bf16 h = f2bf(v);
        hi[i] = h;
        lo[i] = f2bf(v - bf2f(h));
    }
}
// enc_Wih0 [1024,457] -> padded [1024,480] hi/lo
__global__ __launch_bounds__(256) void split_pad_k(const float* __restrict__ src,
                                                   bf16* __restrict__ hi,
                                                   bf16* __restrict__ lo) {
    const int n = blockIdx.x;
    const float* s = src + (size_t)n * LIN;
    for (int k = threadIdx.x; k < LPAD; k += 256) {
        float v = (k < LIN) ? s[k] : 0.f;
        bf16 h = f2bf(v);
        hi[(size_t)n * LPAD + k] = h;
        lo[(size_t)n * LPAD + k] = f2bf(v - bf2f(h));
    }
}

// --------- 3-pass split GEMM inner loop (pointers pre-offset +quad*8) ------
// A[m=lane&15][k=quad*8+j], B[k=quad*8+j][n=lane&15], D col=lane&15 row=quad*4+r
static __device__ __forceinline__ void gemm3(const bf16* __restrict__ ah_,
                                             const bf16* __restrict__ al_,
                                             const bf16* __restrict__ wh_,
                                             const bf16* __restrict__ wl_,
                                             int K, int ldw, f32x4 acc[4]) {
    for (int k0 = 0; k0 < K; k0 += 32) {
        bf16x8 ah = *(const bf16x8*)(ah_ + k0);
        bf16x8 al = *(const bf16x8*)(al_ + k0);
#pragma unroll
        for (int i = 0; i < 4; i++) {
            bf16x8 wh = *(const bf16x8*)(wh_ + (size_t)i * 16 * ldw + k0);
            bf16x8 wl = *(const bf16x8*)(wl_ + (size_t)i * 16 * ldw + k0);
            acc[i] = MFMA(ah, wh, acc[i]);
            acc[i] = MFMA(al, wh, acc[i]);
            acc[i] = MFMA(ah, wl, acc[i]);
        }
    }
}

static __device__ __forceinline__ void store_tanh(f32x4 acc[4], int m0, int n0,
                                                  int lm, int quad,
                                                  bf16* __restrict__ ohi,
                                                  bf16* __restrict__ olo) {
#pragma unroll
    for (int i = 0; i < 4; i++) {
        int n = n0 + 16 * i + lm;
#pragma unroll
        for (int r = 0; r < 4; r++) {
            int m = m0 + quad * 4 + r;
            float h = tanhf(acc[i][r]);
            bf16 hb = f2bf(h);
            ohi[(size_t)m * Hh + n] = hb;
            olo[(size_t)m * Hh + n] = f2bf(h - bf2f(hb));
        }
    }
}

// --------------------------- encoder layer 0 -------------------------------
// h0' = tanh(x_t @ Wih0^T + h0 @ Whh0^T + b0); x fp32, split on the fly
__global__ __launch_bounds__(256) void enc_step0_k(
    const float* __restrict__ x, int t,
    const bf16* __restrict__ w0hi, const bf16* __restrict__ w0lo,
    const bf16* __restrict__ hhi, const bf16* __restrict__ hlo,
    const bf16* __restrict__ uhi, const bf16* __restrict__ ulo,
    const float* __restrict__ bias,
    bf16* __restrict__ ohi, bf16* __restrict__ olo) {
    const int lane = threadIdx.x & 63, wave = threadIdx.x >> 6;
    const int lm = lane & 15, quad = lane >> 4;
    const int m0 = blockIdx.x * 64 + wave * 16;
    const int n0 = blockIdx.y * 64;
    f32x4 acc[4];
#pragma unroll
    for (int i = 0; i < 4; i++) {
        float bv = bias[n0 + 16 * i + lm];
        acc[i] = (f32x4){bv, bv, bv, bv};
    }
    const float* xrow = x + ((size_t)(m0 + lm) * Tt + t) * LIN;
    const bf16* w0h = w0hi + (size_t)(n0 + lm) * LPAD + quad * 8;
    const bf16* w0l = w0lo + (size_t)(n0 + lm) * LPAD + quad * 8;
    for (int k0 = 0; k0 < LPAD; k0 += 32) {
        const int kb = k0 + quad * 8;
        bf16x8 ah, al;
#pragma unroll
        for (int j = 0; j < 8; j++) {
            float v = (kb + j < LIN) ? xrow[kb + j] : 0.f;
            bf16 h = f2bf(v);
            ah[j] = h;
            al[j] = f2bf(v - bf2f(h));
        }
#pragma unroll
        for (int i = 0; i < 4; i++) {
            bf16x8 wh = *(const bf16x8*)(w0h + (size_t)i * 16 * LPAD + k0);
            bf16x8 wl = *(const bf16x8*)(w0l + (size_t)i * 16 * LPAD + k0);
            acc[i] = MFMA(ah, wh, acc[i]);
            acc[i] = MFMA(al, wh, acc[i]);
            acc[i] = MFMA(ah, wl, acc[i]);
        }
    }
    gemm3(hhi + (size_t)(m0 + lm) * Hh + quad * 8,
          hlo + (size_t)(m0 + lm) * Hh + quad * 8,
          uhi + (size_t)(n0 + lm) * Hh + quad * 8,
          ulo + (size_t)(n0 + lm) * Hh + quad * 8, Hh, Hh, acc);
    store_tanh(acc, m0, n0, lm, quad, ohi, olo);
}

// ------------------ layer-1 step (encoder L1 and decoder L1) ---------------
__global__ __launch_bounds__(256) void rnn2_step_k(
    const bf16* __restrict__ xhi, const bf16* __restrict__ xlo,
    const bf16* __restrict__ wihhi, const bf16* __restrict__ wihlo,
    const bf16* __restrict__ hhi, const bf16* __restrict__ hlo,
    const bf16* __restrict__ whhhi, const bf16* __restrict__ whhlo,
    const float* __restrict__ bias,
    bf16* __restrict__ ohi, bf16* __restrict__ olo) {
    const int lane = threadIdx.x & 63, wave = threadIdx.x >> 6;
    const int lm = lane & 15, quad = lane >> 4;
    const int m0 = blockIdx.x * 64 + wave * 16;
    const int n0 = blockIdx.y * 64;
    f32x4 acc[4];
#pragma unroll
    for (int i = 0; i < 4; i++) {
        float bv = bias[n0 + 16 * i + lm];
        acc[i] = (f32x4){bv, bv, bv, bv};
    }
    gemm3(xhi + (size_t)(m0 + lm) * Hh + quad * 8,
          xlo + (size_t)(m0 + lm) * Hh + quad * 8,
          wihhi + (size_t)(n0 + lm) * Hh + quad * 8,
          wihlo + (size_t)(n0 + lm) * Hh + quad * 8, Hh, Hh, acc);
    gemm3(hhi + (size_t)(m0 + lm) * Hh + quad * 8,
          hlo + (size_t)(m0 + lm) * Hh + quad * 8,
          whhhi + (size_t)(n0 + lm) * Hh + quad * 8,
          whhlo + (size_t)(n0 + lm) * Hh + quad * 8, Hh, Hh, acc);
    store_tanh(acc, m0, n0, lm, quad, ohi, olo);
}

// ------- one-time: EP[v][n] = emb[v] @ dec_Wih0^T + dec_b0 (fp64->fp32) ----
__global__ __launch_bounds__(256) void dec_pre_k(const float* __restrict__ emb,
                                                 const float* __restrict__ W,
                                                 const float* __restrict__ b,
                                                 float* __restrict__ EP) {
    const int n = blockIdx.x * 256 + threadIdx.x;
    const int v = blockIdx.y * 4;
    double acc[4];
    const double bv = (double)b[n];
    acc[0] = acc[1] = acc[2] = acc[3] = bv;
    const float* wr = W + (size_t)n * Hh;
#pragma unroll 4
    for (int k = 0; k < Hh; k++) {
        double wv = (double)wr[k];
        acc[0] = fma((double)emb[(size_t)(v + 0) * Hh + k], wv, acc[0]);
        acc[1] = fma((double)emb[(size_t)(v + 1) * Hh + k], wv, acc[1]);
        acc[2] = fma((double)emb[(size_t)(v + 2) * Hh + k], wv, acc[2]);
        acc[3] = fma((double)emb[(size_t)(v + 3) * Hh + k], wv, acc[3]);
    }
#pragma unroll
    for (int r = 0; r < 4; r++) EP[(size_t)(v + r) * Hh + n] = (float)acc[r];
}

// ---------- decoder layer 0: h0' = tanh(EP[tok] + h0 @ dec_Whh0^T) ---------
__global__ __launch_bounds__(256) void dec_step0_k(
    const float* __restrict__ EP, const int* __restrict__ tok,
    const bf16* __restrict__ hhi, const bf16* __restrict__ hlo,
    const bf16* __restrict__ uhi, const bf16* __restrict__ ulo,
    bf16* __restrict__ ohi, bf16* __restrict__ olo) {
    const int lane = threadIdx.x & 63, wave = threadIdx.x >> 6;
    const int lm = lane & 15, quad = lane >> 4;
    const int m0 = blockIdx.x * 64 + wave * 16;
    const int n0 = blockIdx.y * 64;
    f32x4 acc[4];
#pragma unroll
    for (int i = 0; i < 4; i++) acc[i] = (f32x4){0.f, 0.f, 0.f, 0.f};
    gemm3(hhi + (size_t)(m0 + lm) * Hh + quad * 8,
          hlo + (size_t)(m0 + lm) * Hh + quad * 8,
          uhi + (size_t)(n0 + lm) * Hh + quad * 8,
          ulo + (size_t)(n0 + lm) * Hh + quad * 8, Hh, Hh, acc);
    int tk[4];
#pragma unroll
    for (int r = 0; r < 4; r++) tk[r] = tok[m0 + quad * 4 + r];
#pragma unroll
    for (int i = 0; i < 4; i++) {
        int n = n0 + 16 * i + lm;
#pragma unroll
        for (int r = 0; r < 4; r++) {
            int m = m0 + quad * 4 + r;
            float h = tanhf(acc[i][r] + EP[(size_t)tk[r] * Hh + n]);
            bf16 hb = f2bf(h);
            ohi[(size_t)m * Hh + n] = hb;
            olo[(size_t)m * Hh + n] = f2bf(h - bf2f(hb));
        }
    }
}

// ---- fc + argmax + FP32 logit store; fp64 dot (token-deciding path) -------
__global__ __launch_bounds__(256) void dec_fc_k(
    const bf16* __restrict__ h1hi, const bf16* __restrict__ h1lo,
    const float* __restrict__ fcw, const float* __restrict__ fcb,
    float* __restrict__ out, int* __restrict__ tok, int t) {
    __shared__ double hrow[4][Hh];
    const int w = threadIdx.x >> 6, v = threadIdx.x & 63;
    const int b = blockIdx.x * 4 + w;
    for (int k = v; k < Hh; k += 64)
        hrow[w][k] = (double)bf2f(h1hi[(size_t)b * Hh + k]) +
                     (double)bf2f(h1lo[(size_t)b * Hh + k]);
    __syncthreads();
    const float* wr = fcw + (size_t)v * Hh;
    double acc = (double)fcb[v];
#pragma unroll 4
    for (int k = 0; k < Hh; k++) acc = fma(hrow[w][k], (double)wr[k], acc);
    out[(size_t)b * (Vv * ML) + (size_t)v * ML + t] = (float)acc;
    // wave argmax over V=64 lanes, first-index tiebreak (np.argmax)
    double bvv = acc;
    int bi = v;
#pragma unroll
    for (int s = 1; s < 64; s <<= 1) {
        double ov = __shfl_xor(bvv, s, 64);
        int oi = __shfl_xor(bi, s, 64);
        if (ov > bvv || (ov == bvv && oi < bi)) { bvv = ov; bi = oi; }
    }
    if (v == 0) tok[b] = bi;
}

// ------------------------- final hidden output (fp32) ----------------------
__global__ __launch_bounds__(256) void write_hidden_k(
    const bf16* __restrict__ a1, const bf16* __restrict__ a2,
    const bf16* __restrict__ b1, const bf16* __restrict__ b2,
    float* __restrict__ out) {
    int i = blockIdx.x * 256 + threadIdx.x;   // B*H = 262144 per layer
    const size_t base = (size_t)Bb * Vv * ML;
    out[base + i] = bf2f(a1[i]) + bf2f(a2[i]);
    out[base + (size_t)Bb * Hh + i] = bf2f(b1[i]) + bf2f(b2[i]);
}

// ---------------------------------------------------------------------------
extern "C" void kernel_launch(void* const* d_in, const int* in_sizes, int n_in,
                              void* d_out, int out_size, void* d_ws, size_t ws_size,
                              hipStream_t stream) {
    const float* x   = (const float*)d_in[0];
    const float* emb = (const float*)d_in[1];
    const float* eW0 = (const float*)d_in[2];
    const float* eU0 = (const float*)d_in[3];
    const float* eb0 = (const float*)d_in[4];
    const float* eW1 = (const float*)d_in[5];
    const float* eU1 = (const float*)d_in[6];
    const float* eb1 = (const float*)d_in[7];
    const float* dW0 = (const float*)d_in[8];
    const float* dU0 = (const float*)d_in[9];
    const float* db0 = (const float*)d_in[10];
    const float* dW1 = (const float*)d_in[11];
    const float* dU1 = (const float*)d_in[12];
    const float* db1 = (const float*)d_in[13];
    const float* fcw = (const float*)d_in[14];
    const float* fcb = (const float*)d_in[15];
    (void)in_sizes; (void)n_in; (void)out_size; (void)ws_size;

    char* ws = (char*)d_ws;
    const size_t SB = (size_t)Bb * Hh * 2;      // 512 KB per state component
    const size_t WB = (size_t)Hh * Hh * 2;      // 2 MB per weight component
    bf16 *h0c[2][2], *h1c[2][2];                // [buf][hi/lo]
    size_t o = 0;
    for (int c = 0; c < 2; c++) { h0c[0][c] = (bf16*)(ws + o); o += SB; }
    for (int c = 0; c < 2; c++) { h1c[0][c] = (bf16*)(ws + o); o += SB; }
    int* tok = (int*)(ws + o); o += 4096;
    const size_t zero_bytes = o;                // initial state + start tokens
    for (int c = 0; c < 2; c++) { h0c[1][c] = (bf16*)(ws + o); o += SB; }
    for (int c = 0; c < 2; c++) { h1c[1][c] = (bf16*)(ws + o); o += SB; }
    float* EP = (float*)(ws + o); o += (size_t)Vv * Hh * 4;
    bf16* w0s[2];
    for (int c = 0; c < 2; c++) { w0s[c] = (bf16*)(ws + o); o += (size_t)Hh * LPAD * 2; }
    bf16 *eU0s[2], *eW1s[2], *eU1s[2], *dU0s[2], *dW1s[2], *dU1s[2];
    for (int c = 0; c < 2; c++) { eU0s[c] = (bf16*)(ws + o); o += WB; }
    for (int c = 0; c < 2; c++) { eW1s[c] = (bf16*)(ws + o); o += WB; }
    for (int c = 0; c < 2; c++) { eU1s[c] = (bf16*)(ws + o); o += WB; }
    for (int c = 0; c < 2; c++) { dU0s[c] = (bf16*)(ws + o); o += WB; }
    for (int c = 0; c < 2; c++) { dW1s[c] = (bf16*)(ws + o); o += WB; }
    for (int c = 0; c < 2; c++) { dU1s[c] = (bf16*)(ws + o); o += WB; }
    // total ~31 MB

    hipMemsetAsync(ws, 0, zero_bytes, stream);
    const int NSQ = Hh * Hh;
    split_pad_k<<<dim3(Hh), 256, 0, stream>>>(eW0, w0s[0], w0s[1]);
    split_k<<<dim3(NSQ / 256), 256, 0, stream>>>(eU0, eU0s[0], eU0s[1], NSQ);
    split_k<<<dim3(NSQ / 256), 256, 0, stream>>>(eW1, eW1s[0], eW1s[1], NSQ);
    split_k<<<dim3(NSQ / 256), 256, 0, stream>>>(eU1, eU1s[0], eU1s[1], NSQ);
    split_k<<<dim3(NSQ / 256), 256, 0, stream>>>(dU0, dU0s[0], dU0s[1], NSQ);
    split_k<<<dim3(NSQ / 256), 256, 0, stream>>>(dW1, dW1s[0], dW1s[1], NSQ);
    split_k<<<dim3(NSQ / 256), 256, 0, stream>>>(dU1, dU1s[0], dU1s[1], NSQ);

    dim3 g(4, 16), blk(256);
    float* out = (float*)d_out;
    for (int t = 0; t < Tt; t++) {
        int in = t & 1, op = in ^ 1;
        enc_step0_k<<<g, blk, 0, stream>>>(x, t, w0s[0], w0s[1],
            h0c[in][0], h0c[in][1], eU0s[0], eU0s[1], eb0,
            h0c[op][0], h0c[op][1]);
        rnn2_step_k<<<g, blk, 0, stream>>>(
            h0c[op][0], h0c[op][1], eW1s[0], eW1s[1],
            h1c[in][0], h1c[in][1], eU1s[0], eU1s[1], eb1,
            h1c[op][0], h1c[op][1]);
    }
    dec_pre_k<<<dim3(Hh / 256, Vv / 4), blk, 0, stream>>>(emb, dW0, db0, EP);
    for (int s = 0; s < ML; s++) {
        int in = s & 1, op = in ^ 1;
        dec_step0_k<<<g, blk, 0, stream>>>(EP, tok,
            h0c[in][0], h0c[in][1], dU0s[0], dU0s[1],
            h0c[op][0], h0c[op][1]);
        rnn2_step_k<<<g, blk, 0, stream>>>(
            h0c[op][0], h0c[op][1], dW1s[0], dW1s[1],
            h1c[in][0], h1c[in][1], dU1s[0], dU1s[1], db1,
            h1c[op][0], h1c[op][1]);
        dec_fc_k<<<dim3(Bb / 4), blk, 0, stream>>>(
            h1c[op][0], h1c[op][1], fcw, fcb, out, tok, s);
    }
    write_hidden_k<<<dim3(Bb * Hh / 256), blk, 0, stream>>>(
        h0c[0][0], h0c[0][1], h1c[0][0], h1c[0][1], out);
}

// Round 7
// 19638.200 us; speedup vs baseline: 2.5169x; 1.5771x over previous
//
#include <hip/hip_runtime.h>
#include <math.h>

// Trajectory2seq: 2-layer tanh RNN encoder (T=128, B=256, H=1024) + greedy
// decoder (64 steps). fp32 in / fp32 out. Recurrent GEMMs: bf16 MFMA,
// 2-way hi/lo split (3 passes) -> ~1e-5 logit error (measured argmax margin
// ~1e-3, round 5). Round-7 change: weights pre-packed into MFMA-fragment
// order so every W load is one coalesced 1KB wave transaction (was 16
// scattered 64B lines); grid swizzled n-major for XCD L2 affinity.

#define Bb   256
#define Tt   128
#define Hh   1024
#define Vv   64
#define LIN  457
#define LPAD 480   // 457 padded to 15*32
#define ML   64
#define NKB_H  32  // K=1024 -> 32 k-blocks of 32
#define NKB_X  15  // K=480  -> 15 k-blocks

typedef __bf16 bf16;
typedef __bf16 bf16x8 __attribute__((ext_vector_type(8)));
typedef float  f32x4  __attribute__((ext_vector_type(4)));

static __device__ __forceinline__ float bf2f(bf16 x) {
    unsigned short u = __builtin_bit_cast(unsigned short, x);
    unsigned int w = ((unsigned int)u) << 16;
    return __builtin_bit_cast(float, w);
}
static __device__ __forceinline__ unsigned short f2bfbits(float f) {
    unsigned int u = __builtin_bit_cast(unsigned int, f);
    u = u + 0x7FFFu + ((u >> 16) & 1u);   // RNE (finite only)
    return (unsigned short)(u >> 16);
}
static __device__ __forceinline__ bf16 f2bf(float f) {
    return __builtin_bit_cast(bf16, f2bfbits(f));
}

#define MFMA(a, b, c) __builtin_amdgcn_mfma_f32_16x16x32_bf16((a), (b), (c), 0, 0, 0)

// ---- one-time: fp32 W[N][K] -> packed hi/lo fragments ---------------------
// layout: frag[(nt*nkb + kb)*64 + lane] (16B each), lane=(quad<<4)|lm holds
// W[nt*16+lm][kb*32+quad*8 .. +7]  == MFMA B-operand fragment for n=lm.
__global__ __launch_bounds__(256) void pack_w_k(const float* __restrict__ src,
                                                bf16* __restrict__ hp,
                                                bf16* __restrict__ lp,
                                                int nkb, int src_ld, int kmax) {
    const int tid = blockIdx.x * 256 + threadIdx.x;   // == frag index
    const int lane = tid & 63;
    const int kb = (tid >> 6) % nkb;
    const int nt = tid / (64 * nkb);
    if (nt >= 64) return;
    const int row = nt * 16 + (lane & 15);
    const int k0 = kb * 32 + (lane >> 4) * 8;
    const float* s = src + (size_t)row * src_ld;
    bf16x8 h8, l8;
#pragma unroll
    for (int j = 0; j < 8; j++) {
        float v = (k0 + j < kmax) ? s[k0 + j] : 0.f;
        bf16 h = f2bf(v);
        h8[j] = h;
        l8[j] = f2bf(v - bf2f(h));
    }
    *(bf16x8*)(hp + (size_t)tid * 8) = h8;
    *(bf16x8*)(lp + (size_t)tid * 8) = l8;
}

// ---- 3-pass packed GEMM inner loop ----------------------------------------
// A ptrs pre-offset to (m0+lm)*Hh + quad*8 (row-major state);
// W ptrs pre-offset to nt0*nkb*512 + lane*8 (packed fragments).
static __device__ __forceinline__ void gemm3p(const bf16* __restrict__ ah_,
                                              const bf16* __restrict__ al_,
                                              const bf16* __restrict__ wh_,
                                              const bf16* __restrict__ wl_,
                                              int nkb, f32x4 acc[4]) {
    for (int kb = 0; kb < nkb; kb++) {
        bf16x8 ah = *(const bf16x8*)(ah_ + kb * 32);
        bf16x8 al = *(const bf16x8*)(al_ + kb * 32);
#pragma unroll
        for (int i = 0; i < 4; i++) {
            const size_t off = ((size_t)i * nkb + kb) * 512;
            bf16x8 wh = *(const bf16x8*)(wh_ + off);
            bf16x8 wl = *(const bf16x8*)(wl_ + off);
            acc[i] = MFMA(ah, wh, acc[i]);
            acc[i] = MFMA(al, wh, acc[i]);
            acc[i] = MFMA(ah, wl, acc[i]);
        }
    }
}

static __device__ __forceinline__ void store_tanh(f32x4 acc[4], int m0, int n0,
                                                  int lm, int quad,
                                                  bf16* __restrict__ ohi,
                                                  bf16* __restrict__ olo) {
#pragma unroll
    for (int i = 0; i < 4; i++) {
        int n = n0 + 16 * i + lm;
#pragma unroll
        for (int r = 0; r < 4; r++) {
            int m = m0 + quad * 4 + r;
            float h = tanhf(acc[i][r]);
            bf16 hb = f2bf(h);
            ohi[(size_t)m * Hh + n] = hb;
            olo[(size_t)m * Hh + n] = f2bf(h - bf2f(hb));
        }
    }
}

// --------------------------- encoder layer 0 -------------------------------
// h0' = tanh(x_t @ W0^T + h0 @ U0^T + b0); x fp32 split on the fly
__global__ __launch_bounds__(256) void enc_step0_k(
    const float* __restrict__ x, int t,
    const bf16* __restrict__ w0h, const bf16* __restrict__ w0l,
    const bf16* __restrict__ hhi, const bf16* __restrict__ hlo,
    const bf16* __restrict__ uh, const bf16* __restrict__ ul,
    const float* __restrict__ bias,
    bf16* __restrict__ ohi, bf16* __restrict__ olo) {
    const int lane = threadIdx.x & 63, wave = threadIdx.x >> 6;
    const int lm = lane & 15, quad = lane >> 4;
    const int n0 = blockIdx.x * 64;          // n-major grid for XCD affinity
    const int m0 = blockIdx.y * 64 + wave * 16;
    const int nt0 = blockIdx.x * 4;
    f32x4 acc[4];
#pragma unroll
    for (int i = 0; i < 4; i++) {
        float bv = bias[n0 + 16 * i + lm];
        acc[i] = (f32x4){bv, bv, bv, bv};
    }
    const float* xrow = x + ((size_t)(m0 + lm) * Tt + t) * LIN;
    const bf16* w0h_ = w0h + (size_t)nt0 * NKB_X * 512 + lane * 8;
    const bf16* w0l_ = w0l + (size_t)nt0 * NKB_X * 512 + lane * 8;
    for (int kb = 0; kb < NKB_X; kb++) {
        const int kx = kb * 32 + quad * 8;
        bf16x8 ah, al;
#pragma unroll
        for (int j = 0; j < 8; j++) {
            float v = (kx + j < LIN) ? xrow[kx + j] : 0.f;
            bf16 h = f2bf(v);
            ah[j] = h;
            al[j] = f2bf(v - bf2f(h));
        }
#pragma unroll
        for (int i = 0; i < 4; i++) {
            const size_t off = ((size_t)i * NKB_X + kb) * 512;
            bf16x8 wh = *(const bf16x8*)(w0h_ + off);
            bf16x8 wl = *(const bf16x8*)(w0l_ + off);
            acc[i] = MFMA(ah, wh, acc[i]);
            acc[i] = MFMA(al, wh, acc[i]);
            acc[i] = MFMA(ah, wl, acc[i]);
        }
    }
    gemm3p(hhi + (size_t)(m0 + lm) * Hh + quad * 8,
           hlo + (size_t)(m0 + lm) * Hh + quad * 8,
           uh + (size_t)nt0 * NKB_H * 512 + lane * 8,
           ul + (size_t)nt0 * NKB_H * 512 + lane * 8, NKB_H, acc);
    store_tanh(acc, m0, n0, lm, quad, ohi, olo);
}

// ------------------ layer-1 step (encoder L1 and decoder L1) ---------------
__global__ __launch_bounds__(256) void rnn2_step_k(
    const bf16* __restrict__ xhi, const bf16* __restrict__ xlo,
    const bf16* __restrict__ wih, const bf16* __restrict__ wil,
    const bf16* __restrict__ hhi, const bf16* __restrict__ hlo,
    const bf16* __restrict__ whh, const bf16* __restrict__ whl,
    const float* __restrict__ bias,
    bf16* __restrict__ ohi, bf16* __restrict__ olo) {
    const int lane = threadIdx.x & 63, wave = threadIdx.x >> 6;
    const int lm = lane & 15, quad = lane >> 4;
    const int n0 = blockIdx.x * 64;
    const int m0 = blockIdx.y * 64 + wave * 16;
    const int nt0 = blockIdx.x * 4;
    f32x4 acc[4];
#pragma unroll
    for (int i = 0; i < 4; i++) {
        float bv = bias[n0 + 16 * i + lm];
        acc[i] = (f32x4){bv, bv, bv, bv};
    }
    gemm3p(xhi + (size_t)(m0 + lm) * Hh + quad * 8,
           xlo + (size_t)(m0 + lm) * Hh + quad * 8,
           wih + (size_t)nt0 * NKB_H * 512 + lane * 8,
           wil + (size_t)nt0 * NKB_H * 512 + lane * 8, NKB_H, acc);
    gemm3p(hhi + (size_t)(m0 + lm) * Hh + quad * 8,
           hlo + (size_t)(m0 + lm) * Hh + quad * 8,
           whh + (size_t)nt0 * NKB_H * 512 + lane * 8,
           whl + (size_t)nt0 * NKB_H * 512 + lane * 8, NKB_H, acc);
    store_tanh(acc, m0, n0, lm, quad, ohi, olo);
}

// ------- one-time: EP[v][n] = emb[v] @ dec_Wih0^T + dec_b0 (fp64->fp32) ----
__global__ __launch_bounds__(256) void dec_pre_k(const float* __restrict__ emb,
                                                 const float* __restrict__ W,
                                                 const float* __restrict__ b,
                                                 float* __restrict__ EP) {
    const int n = blockIdx.x * 256 + threadIdx.x;
    const int v = blockIdx.y * 4;
    double acc[4];
    const double bv = (double)b[n];
    acc[0] = acc[1] = acc[2] = acc[3] = bv;
    const float* wr = W + (size_t)n * Hh;
#pragma unroll 4
    for (int k = 0; k < Hh; k++) {
        double wv = (double)wr[k];
        acc[0] = fma((double)emb[(size_t)(v + 0) * Hh + k], wv, acc[0]);
        acc[1] = fma((double)emb[(size_t)(v + 1) * Hh + k], wv, acc[1]);
        acc[2] = fma((double)emb[(size_t)(v + 2) * Hh + k], wv, acc[2]);
        acc[3] = fma((double)emb[(size_t)(v + 3) * Hh + k], wv, acc[3]);
    }
#pragma unroll
    for (int r = 0; r < 4; r++) EP[(size_t)(v + r) * Hh + n] = (float)acc[r];
}

// ---------- decoder layer 0: h0' = tanh(EP[tok] + h0 @ dec_Whh0^T) ---------
__global__ __launch_bounds__(256) void dec_step0_k(
    const float* __restrict__ EP, const int* __restrict__ tok,
    const bf16* __restrict__ hhi, const bf16* __restrict__ hlo,
    const bf16* __restrict__ uh, const bf16* __restrict__ ul,
    bf16* __restrict__ ohi, bf16* __restrict__ olo) {
    const int lane = threadIdx.x & 63, wave = threadIdx.x >> 6;
    const int lm = lane & 15, quad = lane >> 4;
    const int n0 = blockIdx.x * 64;
    const int m0 = blockIdx.y * 64 + wave * 16;
    const int nt0 = blockIdx.x * 4;
    f32x4 acc[4];
#pragma unroll
    for (int i = 0; i < 4; i++) acc[i] = (f32x4){0.f, 0.f, 0.f, 0.f};
    gemm3p(hhi + (size_t)(m0 + lm) * Hh + quad * 8,
           hlo + (size_t)(m0 + lm) * Hh + quad * 8,
           uh + (size_t)nt0 * NKB_H * 512 + lane * 8,
           ul + (size_t)nt0 * NKB_H * 512 + lane * 8, NKB_H, acc);
    int tk[4];
#pragma unroll
    for (int r = 0; r < 4; r++) tk[r] = tok[m0 + quad * 4 + r];
#pragma unroll
    for (int i = 0; i < 4; i++) {
        int n = n0 + 16 * i + lm;
#pragma unroll
        for (int r = 0; r < 4; r++) {
            int m = m0 + quad * 4 + r;
            float h = tanhf(acc[i][r] + EP[(size_t)tk[r] * Hh + n]);
            bf16 hb = f2bf(h);
            ohi[(size_t)m * Hh + n] = hb;
            olo[(size_t)m * Hh + n] = f2bf(h - bf2f(hb));
        }
    }
}

// ---- fc + argmax + FP32 logit store; fp64 dot (token-deciding path) -------
__global__ __launch_bounds__(256) void dec_fc_k(
    const bf16* __restrict__ h1hi, const bf16* __restrict__ h1lo,
    const float* __restrict__ fcw, const float* __restrict__ fcb,
    float* __restrict__ out, int* __restrict__ tok, int t) {
    __shared__ double hrow[4][Hh];
    const int w = threadIdx.x >> 6, v = threadIdx.x & 63;
    const int b = blockIdx.x * 4 + w;
    for (int k = v; k < Hh; k += 64)
        hrow[w][k] = (double)bf2f(h1hi[(size_t)b * Hh + k]) +
                     (double)bf2f(h1lo[(size_t)b * Hh + k]);
    __syncthreads();
    const float* wr = fcw + (size_t)v * Hh;
    double acc = (double)fcb[v];
#pragma unroll 4
    for (int k = 0; k < Hh; k++) acc = fma(hrow[w][k], (double)wr[k], acc);
    out[(size_t)b * (Vv * ML) + (size_t)v * ML + t] = (float)acc;
    double bvv = acc;
    int bi = v;
#pragma unroll
    for (int s = 1; s < 64; s <<= 1) {
        double ov = __shfl_xor(bvv, s, 64);
        int oi = __shfl_xor(bi, s, 64);
        if (ov > bvv || (ov == bvv && oi < bi)) { bvv = ov; bi = oi; }
    }
    if (v == 0) tok[b] = bi;
}

// ------------------------- final hidden output (fp32) ----------------------
__global__ __launch_bounds__(256) void write_hidden_k(
    const bf16* __restrict__ a1, const bf16* __restrict__ a2,
    const bf16* __restrict__ b1, const bf16* __restrict__ b2,
    float* __restrict__ out) {
    int i = blockIdx.x * 256 + threadIdx.x;   // B*H = 262144 per layer
    const size_t base = (size_t)Bb * Vv * ML;
    out[base + i] = bf2f(a1[i]) + bf2f(a2[i]);
    out[base + (size_t)Bb * Hh + i] = bf2f(b1[i]) + bf2f(b2[i]);
}

// ---------------------------------------------------------------------------
extern "C" void kernel_launch(void* const* d_in, const int* in_sizes, int n_in,
                              void* d_out, int out_size, void* d_ws, size_t ws_size,
                              hipStream_t stream) {
    const float* x   = (const float*)d_in[0];
    const float* emb = (const float*)d_in[1];
    const float* eW0 = (const float*)d_in[2];
    const float* eU0 = (const float*)d_in[3];
    const float* eb0 = (const float*)d_in[4];
    const float* eW1 = (const float*)d_in[5];
    const float* eU1 = (const float*)d_in[6];
    const float* eb1 = (const float*)d_in[7];
    const float* dW0 = (const float*)d_in[8];
    const float* dU0 = (const float*)d_in[9];
    const float* db0 = (const float*)d_in[10];
    const float* dW1 = (const float*)d_in[11];
    const float* dU1 = (const float*)d_in[12];
    const float* db1 = (const float*)d_in[13];
    const float* fcw = (const float*)d_in[14];
    const float* fcb = (const float*)d_in[15];
    (void)in_sizes; (void)n_in; (void)out_size; (void)ws_size;

    char* ws = (char*)d_ws;
    const size_t SB = (size_t)Bb * Hh * 2;          // 512 KB state component
    const size_t WPK = (size_t)64 * NKB_H * 512 * 2;// 2 MB packed square comp
    const size_t WPX = (size_t)64 * NKB_X * 512 * 2;// 0.94 MB packed w0 comp
    bf16 *h0c[2][2], *h1c[2][2];
    size_t o = 0;
    for (int c = 0; c < 2; c++) { h0c[0][c] = (bf16*)(ws + o); o += SB; }
    for (int c = 0; c < 2; c++) { h1c[0][c] = (bf16*)(ws + o); o += SB; }
    int* tok = (int*)(ws + o); o += 4096;
    const size_t zero_bytes = o;
    for (int c = 0; c < 2; c++) { h0c[1][c] = (bf16*)(ws + o); o += SB; }
    for (int c = 0; c < 2; c++) { h1c[1][c] = (bf16*)(ws + o); o += SB; }
    float* EP = (float*)(ws + o); o += (size_t)Vv * Hh * 4;
    bf16 *w0p[2];
    for (int c = 0; c < 2; c++) { w0p[c] = (bf16*)(ws + o); o += WPX; }
    bf16 *eU0p[2], *eW1p[2], *eU1p[2], *dU0p[2], *dW1p[2], *dU1p[2];
    for (int c = 0; c < 2; c++) { eU0p[c] = (bf16*)(ws + o); o += WPK; }
    for (int c = 0; c < 2; c++) { eW1p[c] = (bf16*)(ws + o); o += WPK; }
    for (int c = 0; c < 2; c++) { eU1p[c] = (bf16*)(ws + o); o += WPK; }
    for (int c = 0; c < 2; c++) { dU0p[c] = (bf16*)(ws + o); o += WPK; }
    for (int c = 0; c < 2; c++) { dW1p[c] = (bf16*)(ws + o); o += WPK; }
    for (int c = 0; c < 2; c++) { dU1p[c] = (bf16*)(ws + o); o += WPK; }
    // total ~30.5 MB

    hipMemsetAsync(ws, 0, zero_bytes, stream);
    dim3 blk(256);
    const int GSQ = 64 * NKB_H * 64 / 256;   // 512 blocks
    const int GX  = 64 * NKB_X * 64 / 256;   // 240 blocks
    pack_w_k<<<dim3(GX),  blk, 0, stream>>>(eW0, w0p[0],  w0p[1],  NKB_X, LIN, LIN);
    pack_w_k<<<dim3(GSQ), blk, 0, stream>>>(eU0, eU0p[0], eU0p[1], NKB_H, Hh, Hh);
    pack_w_k<<<dim3(GSQ), blk, 0, stream>>>(eW1, eW1p[0], eW1p[1], NKB_H, Hh, Hh);
    pack_w_k<<<dim3(GSQ), blk, 0, stream>>>(eU1, eU1p[0], eU1p[1], NKB_H, Hh, Hh);
    pack_w_k<<<dim3(GSQ), blk, 0, stream>>>(dU0, dU0p[0], dU0p[1], NKB_H, Hh, Hh);
    pack_w_k<<<dim3(GSQ), blk, 0, stream>>>(dW1, dW1p[0], dW1p[1], NKB_H, Hh, Hh);
    pack_w_k<<<dim3(GSQ), blk, 0, stream>>>(dU1, dU1p[0], dU1p[1], NKB_H, Hh, Hh);

    dim3 g(16, 4);   // x = n-tile (XCD round-robin), y = m-tile
    float* out = (float*)d_out;
    for (int t = 0; t < Tt; t++) {
        int in = t & 1, op = in ^ 1;
        enc_step0_k<<<g, blk, 0, stream>>>(x, t, w0p[0], w0p[1],
            h0c[in][0], h0c[in][1], eU0p[0], eU0p[1], eb0,
            h0c[op][0], h0c[op][1]);
        rnn2_step_k<<<g, blk, 0, stream>>>(
            h0c[op][0], h0c[op][1], eW1p[0], eW1p[1],
            h1c[in][0], h1c[in][1], eU1p[0], eU1p[1], eb1,
            h1c[op][0], h1c[op][1]);
    }
    dec_pre_k<<<dim3(Hh / 256, Vv / 4), blk, 0, stream>>>(emb, dW0, db0, EP);
    for (int s = 0; s < ML; s++) {
        int in = s & 1, op = in ^ 1;
        dec_step0_k<<<g, blk, 0, stream>>>(EP, tok,
            h0c[in][0], h0c[in][1], dU0p[0], dU0p[1],
            h0c[op][0], h0c[op][1]);
        rnn2_step_k<<<g, blk, 0, stream>>>(
            h0c[op][0], h0c[op][1], dW1p[0], dW1p[1],
            h1c[in][0], h1c[in][1], dU1p[0], dU1p[1], db1,
            h1c[op][0], h1c[op][1]);
        dec_fc_k<<<dim3(Bb / 4), blk, 0, stream>>>(
            h1c[op][0], h1c[op][1], fcw, fcb, out, tok, s);
    }
    write_hidden_k<<<dim3(Bb * Hh / 256), blk, 0, stream>>>(
        h0c[0][0], h0c[0][1], h1c[0][0], h1c[0][1], out);
}

// Round 8
// 8557.001 us; speedup vs baseline: 5.7762x; 2.2950x over previous
//
#include <hip/hip_runtime.h>
#include <math.h>

// Trajectory2seq: 2-layer tanh RNN encoder (T=128, B=256, H=1024) + greedy
// decoder (64 steps). fp32 in / fp32 out. bf16 MFMA with 2-way hi/lo split
// (3 passes) ~1e-5 logit error vs measured ~1e-3 argmax margin.
// Round-8: latency attack. (1) state kept in packed MFMA-fragment layout ->
// A loads are 1KB coalesced wave transactions; (2) 16x16 wave tiles with the
// two GEMM terms on separate waves + LDS reduce -> 2048 waves = 2 waves/SIMD
// TLP across all 256 CUs; (3) x staged via LDS; 2-stage register pipeline.

#define Bb   256
#define Tt   128
#define Hh   1024
#define Vv   64
#define LIN  457
#define ML   64
#define NKB_H  32   // K=1024 -> 32 k-blocks of 32
#define NKB_X  15   // K=480  -> 15 k-blocks
#define XST  496    // LDS x row stride (bank spread, 16B aligned)

typedef __bf16 bf16;
typedef __bf16 bf16x8 __attribute__((ext_vector_type(8)));
typedef float  f32x4  __attribute__((ext_vector_type(4)));

static __device__ __forceinline__ float bf2f(bf16 x) {
    unsigned short u = __builtin_bit_cast(unsigned short, x);
    unsigned int w = ((unsigned int)u) << 16;
    return __builtin_bit_cast(float, w);
}
static __device__ __forceinline__ unsigned short f2bfbits(float f) {
    unsigned int u = __builtin_bit_cast(unsigned int, f);
    u = u + 0x7FFFu + ((u >> 16) & 1u);   // RNE (finite only)
    return (unsigned short)(u >> 16);
}
static __device__ __forceinline__ bf16 f2bf(float f) {
    return __builtin_bit_cast(bf16, f2bfbits(f));
}

#define MFMA(a, b, c) __builtin_amdgcn_mfma_f32_16x16x32_bf16((a), (b), (c), 0, 0, 0)

// ---- one-time: fp32 W[N][K] -> packed hi/lo fragments ---------------------
// frag[(nt*nkb + kb)*64 + lane]*8+j holds W[nt*16+(lane&15)][kb*32+(lane>>4)*8+j]
__global__ __launch_bounds__(256) void pack_w_k(const float* __restrict__ src,
                                                bf16* __restrict__ hp,
                                                bf16* __restrict__ lp,
                                                int nkb, int src_ld, int kmax) {
    const int tid = blockIdx.x * 256 + threadIdx.x;
    const int lane = tid & 63;
    const int kb = (tid >> 6) % nkb;
    const int nt = tid / (64 * nkb);
    if (nt >= 64) return;
    const int row = nt * 16 + (lane & 15);
    const int k0 = kb * 32 + (lane >> 4) * 8;
    const float* s = src + (size_t)row * src_ld;
    bf16x8 h8, l8;
#pragma unroll
    for (int j = 0; j < 8; j++) {
        float v = (k0 + j < kmax) ? s[k0 + j] : 0.f;
        bf16 h = f2bf(v);
        h8[j] = h;
        l8[j] = f2bf(v - bf2f(h));
    }
    *(bf16x8*)(hp + (size_t)tid * 8) = h8;
    *(bf16x8*)(lp + (size_t)tid * 8) = l8;
}

// ---- pipelined 16x16 gemm over kb range (A and W packed-fragment) ---------
// aBase/alBase: + kb*512 elems; wBase/wlBase: + kb*512 elems.
static __device__ __forceinline__ void gemm_pipe(const bf16* __restrict__ ah,
                                                 const bf16* __restrict__ al,
                                                 const bf16* __restrict__ wh,
                                                 const bf16* __restrict__ wl,
                                                 int kb0, int kb1, f32x4* acc) {
    if (kb0 >= kb1) return;
    bf16x8 cah = *(const bf16x8*)(ah + (size_t)kb0 * 512);
    bf16x8 cal = *(const bf16x8*)(al + (size_t)kb0 * 512);
    bf16x8 cwh = *(const bf16x8*)(wh + (size_t)kb0 * 512);
    bf16x8 cwl = *(const bf16x8*)(wl + (size_t)kb0 * 512);
    for (int kb = kb0; kb < kb1; kb++) {
        bf16x8 nah = cah, nal = cal, nwh = cwh, nwl = cwl;
        if (kb + 1 < kb1) {
            nah = *(const bf16x8*)(ah + (size_t)(kb + 1) * 512);
            nal = *(const bf16x8*)(al + (size_t)(kb + 1) * 512);
            nwh = *(const bf16x8*)(wh + (size_t)(kb + 1) * 512);
            nwl = *(const bf16x8*)(wl + (size_t)(kb + 1) * 512);
        }
        *acc = MFMA(cah, cwh, *acc);
        *acc = MFMA(cal, cwh, *acc);
        *acc = MFMA(cah, cwl, *acc);
        cah = nah; cal = nal; cwh = nwh; cwl = nwl;
    }
}

// packed-state store of 16x16 tile (hi/lo), tanh applied
static __device__ __forceinline__ void store_tile(f32x4 acc, int mt, int nt,
                                                  int lm, int quad,
                                                  bf16* __restrict__ ohi,
                                                  bf16* __restrict__ olo) {
    const int o32 = (nt & 1) * 16 + lm;
    const int kbs = nt >> 1;
    const size_t base = (((size_t)mt * 32 + kbs) * 64 + (o32 >> 3) * 16 + quad * 4) * 8
                        + (o32 & 7);
#pragma unroll
    for (int r = 0; r < 4; r++) {
        float h = tanhf(acc[r]);
        bf16 hb = f2bf(h);
        ohi[base + r * 8] = hb;
        olo[base + r * 8] = f2bf(h - bf2f(hb));
    }
}

// --------------------------- encoder layer 0 -------------------------------
// block: 2 tiles (nt=bx*2+tile, mt=by), 2 waves/tile. role0: bias + x-gemm
// (LDS-staged) + h kb[0,9); role1: h kb[9,32); LDS-reduce; role0 stores.
__global__ __launch_bounds__(256, 2) void enc_step0_k(
    const float* __restrict__ x, int t,
    const bf16* __restrict__ w0h, const bf16* __restrict__ w0l,
    const bf16* __restrict__ hhi, const bf16* __restrict__ hlo,
    const bf16* __restrict__ uh, const bf16* __restrict__ ul,
    const float* __restrict__ bias,
    bf16* __restrict__ ohi, bf16* __restrict__ olo) {
    __shared__ bf16 xh[16 * XST], xl[16 * XST];
    __shared__ float red[2][256];
    const int tid = threadIdx.x;
    const int lane = tid & 63, wave = tid >> 6;
    const int lm = lane & 15, quad = lane >> 4;
    const int tile = wave >> 1, role = wave & 1;
    const int mt = blockIdx.y, nt = blockIdx.x * 2 + tile;
    // stage x rows mt*16..+15 -> LDS hi/lo
    for (int idx = tid; idx < 16 * XST; idx += 256) {
        int row = idx / XST, col = idx - row * XST;
        float v = (col < LIN) ? x[((size_t)(mt * 16 + row) * Tt + t) * LIN + col] : 0.f;
        bf16 h = f2bf(v);
        xh[idx] = h;
        xl[idx] = f2bf(v - bf2f(h));
    }
    __syncthreads();
    f32x4 acc = (f32x4){0.f, 0.f, 0.f, 0.f};
    const bf16* ah = hhi + ((size_t)mt * 2048 + lane) * 8;
    const bf16* al = hlo + ((size_t)mt * 2048 + lane) * 8;
    const bf16* wha = uh + (size_t)nt * NKB_H * 512 + lane * 8;
    const bf16* wla = ul + (size_t)nt * NKB_H * 512 + lane * 8;
    if (role == 0) {
        float bv = bias[nt * 16 + lm];
        acc = (f32x4){bv, bv, bv, bv};
        const bf16* w0h_ = w0h + (size_t)nt * NKB_X * 512 + lane * 8;
        const bf16* w0l_ = w0l + (size_t)nt * NKB_X * 512 + lane * 8;
        for (int kb = 0; kb < NKB_X; kb++) {
            bf16x8 a1 = *(const bf16x8*)(&xh[lm * XST + kb * 32 + quad * 8]);
            bf16x8 a2 = *(const bf16x8*)(&xl[lm * XST + kb * 32 + quad * 8]);
            bf16x8 wh8 = *(const bf16x8*)(w0h_ + (size_t)kb * 512);
            bf16x8 wl8 = *(const bf16x8*)(w0l_ + (size_t)kb * 512);
            acc = MFMA(a1, wh8, acc);
            acc = MFMA(a2, wh8, acc);
            acc = MFMA(a1, wl8, acc);
        }
        gemm_pipe(ah, al, wha, wla, 0, 9, &acc);
    } else {
        gemm_pipe(ah, al, wha, wla, 9, NKB_H, &acc);
        red[tile][lane * 4 + 0] = acc[0];
        red[tile][lane * 4 + 1] = acc[1];
        red[tile][lane * 4 + 2] = acc[2];
        red[tile][lane * 4 + 3] = acc[3];
    }
    __syncthreads();
    if (role == 0) {
#pragma unroll
        for (int r = 0; r < 4; r++) acc[r] += red[tile][lane * 4 + r];
        store_tile(acc, mt, nt, lm, quad, ohi, olo);
    }
}

// ------------------ layer-1 step (encoder L1 and decoder L1) ---------------
// role0: bias + xs@Wi (32 kb); role1: h@Wh (32 kb); reduce; store.
__global__ __launch_bounds__(256, 2) void rnn2_step_k(
    const bf16* __restrict__ xhi, const bf16* __restrict__ xlo,
    const bf16* __restrict__ wih, const bf16* __restrict__ wil,
    const bf16* __restrict__ hhi, const bf16* __restrict__ hlo,
    const bf16* __restrict__ whh, const bf16* __restrict__ whl,
    const float* __restrict__ bias,
    bf16* __restrict__ ohi, bf16* __restrict__ olo) {
    __shared__ float red[2][256];
    const int tid = threadIdx.x;
    const int lane = tid & 63, wave = tid >> 6;
    const int lm = lane & 15, quad = lane >> 4;
    const int tile = wave >> 1, role = wave & 1;
    const int mt = blockIdx.y, nt = blockIdx.x * 2 + tile;
    f32x4 acc = (f32x4){0.f, 0.f, 0.f, 0.f};
    if (role == 0) {
        float bv = bias[nt * 16 + lm];
        acc = (f32x4){bv, bv, bv, bv};
        gemm_pipe(xhi + ((size_t)mt * 2048 + lane) * 8,
                  xlo + ((size_t)mt * 2048 + lane) * 8,
                  wih + (size_t)nt * NKB_H * 512 + lane * 8,
                  wil + (size_t)nt * NKB_H * 512 + lane * 8, 0, NKB_H, &acc);
    } else {
        gemm_pipe(hhi + ((size_t)mt * 2048 + lane) * 8,
                  hlo + ((size_t)mt * 2048 + lane) * 8,
                  whh + (size_t)nt * NKB_H * 512 + lane * 8,
                  whl + (size_t)nt * NKB_H * 512 + lane * 8, 0, NKB_H, &acc);
        red[tile][lane * 4 + 0] = acc[0];
        red[tile][lane * 4 + 1] = acc[1];
        red[tile][lane * 4 + 2] = acc[2];
        red[tile][lane * 4 + 3] = acc[3];
    }
    __syncthreads();
    if (role == 0) {
#pragma unroll
        for (int r = 0; r < 4; r++) acc[r] += red[tile][lane * 4 + r];
        store_tile(acc, mt, nt, lm, quad, ohi, olo);
    }
}

// ------- one-time: EP[v][n] = emb[v] @ dec_Wih0^T + dec_b0 (fp64->fp32) ----
__global__ __launch_bounds__(256) void dec_pre_k(const float* __restrict__ emb,
                                                 const float* __restrict__ W,
                                                 const float* __restrict__ b,
                                                 float* __restrict__ EP) {
    const int n = blockIdx.x * 256 + threadIdx.x;
    const int v = blockIdx.y * 4;
    double acc[4];
    const double bv = (double)b[n];
    acc[0] = acc[1] = acc[2] = acc[3] = bv;
    const float* wr = W + (size_t)n * Hh;
#pragma unroll 4
    for (int k = 0; k < Hh; k++) {
        double wv = (double)wr[k];
        acc[0] = fma((double)emb[(size_t)(v + 0) * Hh + k], wv, acc[0]);
        acc[1] = fma((double)emb[(size_t)(v + 1) * Hh + k], wv, acc[1]);
        acc[2] = fma((double)emb[(size_t)(v + 2) * Hh + k], wv, acc[2]);
        acc[3] = fma((double)emb[(size_t)(v + 3) * Hh + k], wv, acc[3]);
    }
#pragma unroll
    for (int r = 0; r < 4; r++) EP[(size_t)(v + r) * Hh + n] = (float)acc[r];
}

// ---------- decoder layer 0: h0' = tanh(EP[tok] + h0 @ dec_Whh0^T) ---------
// role0: kb[0,16) + EP gather; role1: kb[16,32); reduce; store.
__global__ __launch_bounds__(256, 2) void dec_step0_k(
    const float* __restrict__ EP, const int* __restrict__ tok,
    const bf16* __restrict__ hhi, const bf16* __restrict__ hlo,
    const bf16* __restrict__ uh, const bf16* __restrict__ ul,
    bf16* __restrict__ ohi, bf16* __restrict__ olo) {
    __shared__ float red[2][256];
    const int tid = threadIdx.x;
    const int lane = tid & 63, wave = tid >> 6;
    const int lm = lane & 15, quad = lane >> 4;
    const int tile = wave >> 1, role = wave & 1;
    const int mt = blockIdx.y, nt = blockIdx.x * 2 + tile;
    f32x4 acc = (f32x4){0.f, 0.f, 0.f, 0.f};
    const bf16* ah = hhi + ((size_t)mt * 2048 + lane) * 8;
    const bf16* al = hlo + ((size_t)mt * 2048 + lane) * 8;
    const bf16* wha = uh + (size_t)nt * NKB_H * 512 + lane * 8;
    const bf16* wla = ul + (size_t)nt * NKB_H * 512 + lane * 8;
    if (role == 0) {
        gemm_pipe(ah, al, wha, wla, 0, 16, &acc);
    } else {
        gemm_pipe(ah, al, wha, wla, 16, NKB_H, &acc);
        red[tile][lane * 4 + 0] = acc[0];
        red[tile][lane * 4 + 1] = acc[1];
        red[tile][lane * 4 + 2] = acc[2];
        red[tile][lane * 4 + 3] = acc[3];
    }
    __syncthreads();
    if (role == 0) {
        const int n = nt * 16 + lm;
#pragma unroll
        for (int r = 0; r < 4; r++) {
            int tk = tok[mt * 16 + quad * 4 + r];
            acc[r] += red[tile][lane * 4 + r] + EP[(size_t)tk * Hh + n];
        }
        store_tile(acc, mt, nt, lm, quad, ohi, olo);
    }
}

// ---- fc + argmax + FP32 logit store; fp64 dot (token-deciding path) -------
__global__ __launch_bounds__(256) void dec_fc_k(
    const bf16* __restrict__ h1hi, const bf16* __restrict__ h1lo,
    const float* __restrict__ fcw, const float* __restrict__ fcb,
    float* __restrict__ out, int* __restrict__ tok, int t) {
    __shared__ double hrow[4][Hh];
    const int w = threadIdx.x >> 6, v = threadIdx.x & 63;
    const int b = blockIdx.x * 4 + w;
    const int mt = b >> 4, lmb = b & 15;
    for (int k = v; k < Hh; k += 64) {
        size_t idx = (((size_t)mt * 32 + (k >> 5)) * 64 + ((k >> 3) & 3) * 16 + lmb) * 8
                     + (k & 7);
        hrow[w][k] = (double)bf2f(h1hi[idx]) + (double)bf2f(h1lo[idx]);
    }
    __syncthreads();
    const float* wr = fcw + (size_t)v * Hh;
    double a0 = (v == 0) ? 0.0 : 0.0;
    double acc = (double)fcb[v];
#pragma unroll 4
    for (int k = 0; k < Hh; k++) acc = fma(hrow[w][k], (double)wr[k], acc);
    (void)a0;
    out[(size_t)b * (Vv * ML) + (size_t)v * ML + t] = (float)acc;
    double bvv = acc;
    int bi = v;
#pragma unroll
    for (int s = 1; s < 64; s <<= 1) {
        double ov = __shfl_xor(bvv, s, 64);
        int oi = __shfl_xor(bi, s, 64);
        if (ov > bvv || (ov == bvv && oi < bi)) { bvv = ov; bi = oi; }
    }
    if (v == 0) tok[b] = bi;
}

// ------------------------- final hidden output (fp32) ----------------------
__global__ __launch_bounds__(256) void write_hidden_k(
    const bf16* __restrict__ a1, const bf16* __restrict__ a2,
    const bf16* __restrict__ b1, const bf16* __restrict__ b2,
    float* __restrict__ out) {
    int i = blockIdx.x * 256 + threadIdx.x;   // B*H = 262144 per layer
    const int b = i >> 10, k = i & 1023;
    const size_t idx = (((size_t)(b >> 4) * 32 + (k >> 5)) * 64
                        + ((k >> 3) & 3) * 16 + (b & 15)) * 8 + (k & 7);
    const size_t base = (size_t)Bb * Vv * ML;
    out[base + i] = bf2f(a1[idx]) + bf2f(a2[idx]);
    out[base + (size_t)Bb * Hh + i] = bf2f(b1[idx]) + bf2f(b2[idx]);
}

// ---------------------------------------------------------------------------
extern "C" void kernel_launch(void* const* d_in, const int* in_sizes, int n_in,
                              void* d_out, int out_size, void* d_ws, size_t ws_size,
                              hipStream_t stream) {
    const float* x   = (const float*)d_in[0];
    const float* emb = (const float*)d_in[1];
    const float* eW0 = (const float*)d_in[2];
    const float* eU0 = (const float*)d_in[3];
    const float* eb0 = (const float*)d_in[4];
    const float* eW1 = (const float*)d_in[5];
    const float* eU1 = (const float*)d_in[6];
    const float* eb1 = (const float*)d_in[7];
    const float* dW0 = (const float*)d_in[8];
    const float* dU0 = (const float*)d_in[9];
    const float* db0 = (const float*)d_in[10];
    const float* dW1 = (const float*)d_in[11];
    const float* dU1 = (const float*)d_in[12];
    const float* db1 = (const float*)d_in[13];
    const float* fcw = (const float*)d_in[14];
    const float* fcb = (const float*)d_in[15];
    (void)in_sizes; (void)n_in; (void)out_size; (void)ws_size;

    char* ws = (char*)d_ws;
    const size_t SB = (size_t)Bb * Hh * 2;           // 512 KB state component
    const size_t WPK = (size_t)64 * NKB_H * 512 * 2; // 2 MB packed square comp
    const size_t WPX = (size_t)64 * NKB_X * 512 * 2; // 0.94 MB packed w0 comp
    bf16 *h0c[2][2], *h1c[2][2];
    size_t o = 0;
    for (int c = 0; c < 2; c++) { h0c[0][c] = (bf16*)(ws + o); o += SB; }
    for (int c = 0; c < 2; c++) { h1c[0][c] = (bf16*)(ws + o); o += SB; }
    int* tok = (int*)(ws + o); o += 4096;
    const size_t zero_bytes = o;
    for (int c = 0; c < 2; c++) { h0c[1][c] = (bf16*)(ws + o); o += SB; }
    for (int c = 0; c < 2; c++) { h1c[1][c] = (bf16*)(ws + o); o += SB; }
    float* EP = (float*)(ws + o); o += (size_t)Vv * Hh * 4;
    bf16 *w0p[2];
    for (int c = 0; c < 2; c++) { w0p[c] = (bf16*)(ws + o); o += WPX; }
    bf16 *eU0p[2], *eW1p[2], *eU1p[2], *dU0p[2], *dW1p[2], *dU1p[2];
    for (int c = 0; c < 2; c++) { eU0p[c] = (bf16*)(ws + o); o += WPK; }
    for (int c = 0; c < 2; c++) { eW1p[c] = (bf16*)(ws + o); o += WPK; }
    for (int c = 0; c < 2; c++) { eU1p[c] = (bf16*)(ws + o); o += WPK; }
    for (int c = 0; c < 2; c++) { dU0p[c] = (bf16*)(ws + o); o += WPK; }
    for (int c = 0; c < 2; c++) { dW1p[c] = (bf16*)(ws + o); o += WPK; }
    for (int c = 0; c < 2; c++) { dU1p[c] = (bf16*)(ws + o); o += WPK; }
    // total ~30.5 MB

    hipMemsetAsync(ws, 0, zero_bytes, stream);
    dim3 blk(256);
    const int GSQ = 64 * NKB_H * 64 / 256;   // 512 blocks
    const int GX  = 64 * NKB_X * 64 / 256;   // 240 blocks
    pack_w_k<<<dim3(GX),  blk, 0, stream>>>(eW0, w0p[0],  w0p[1],  NKB_X, LIN, LIN);
    pack_w_k<<<dim3(GSQ), blk, 0, stream>>>(eU0, eU0p[0], eU0p[1], NKB_H, Hh, Hh);
    pack_w_k<<<dim3(GSQ), blk, 0, stream>>>(eW1, eW1p[0], eW1p[1], NKB_H, Hh, Hh);
    pack_w_k<<<dim3(GSQ), blk, 0, stream>>>(eU1, eU1p[0], eU1p[1], NKB_H, Hh, Hh);
    pack_w_k<<<dim3(GSQ), blk, 0, stream>>>(dU0, dU0p[0], dU0p[1], NKB_H, Hh, Hh);
    pack_w_k<<<dim3(GSQ), blk, 0, stream>>>(dW1, dW1p[0], dW1p[1], NKB_H, Hh, Hh);
    pack_w_k<<<dim3(GSQ), blk, 0, stream>>>(dU1, dU1p[0], dU1p[1], NKB_H, Hh, Hh);

    dim3 g(32, 16);  // x = nt-pair (XCD round-robin), y = m-tile; 512 blocks
    float* out = (float*)d_out;
    for (int t = 0; t < Tt; t++) {
        int in = t & 1, op = in ^ 1;
        enc_step0_k<<<g, blk, 0, stream>>>(x, t, w0p[0], w0p[1],
            h0c[in][0], h0c[in][1], eU0p[0], eU0p[1], eb0,
            h0c[op][0], h0c[op][1]);
        rnn2_step_k<<<g, blk, 0, stream>>>(
            h0c[op][0], h0c[op][1], eW1p[0], eW1p[1],
            h1c[in][0], h1c[in][1], eU1p[0], eU1p[1], eb1,
            h1c[op][0], h1c[op][1]);
    }
    dec_pre_k<<<dim3(Hh / 256, Vv / 4), blk, 0, stream>>>(emb, dW0, db0, EP);
    for (int s = 0; s < ML; s++) {
        int in = s & 1, op = in ^ 1;
        dec_step0_k<<<g, blk, 0, stream>>>(EP, tok,
            h0c[in][0], h0c[in][1], dU0p[0], dU0p[1],
            h0c[op][0], h0c[op][1]);
        rnn2_step_k<<<g, blk, 0, stream>>>(
            h0c[op][0], h0c[op][1], dW1p[0], dW1p[1],
            h1c[in][0], h1c[in][1], dU1p[0], dU1p[1], db1,
            h1c[op][0], h1c[op][1]);
        dec_fc_k<<<dim3(Bb / 4), blk, 0, stream>>>(
            h1c[op][0], h1c[op][1], fcw, fcb, out, tok, s);
    }
    write_hidden_k<<<dim3(Bb * Hh / 256), blk, 0, stream>>>(
        h0c[0][0], h0c[0][1], h1c[0][0], h1c[0][1], out);
}